// Round 4
// baseline (74.835 us; speedup 1.0000x reference)
//
#include <hip/hip_runtime.h>

// SO(3) exp map (Rodrigues) + translation -> 4x4 matrix.
// Input:  x[B][6] f32  (w = x[:,0:3], t = x[:,3:6])
// Output: out[B][4][4] f32 row-major.
//
// Round-3 lesson: barrier waitcnt drains were NOT the cost. This round
// removes block coupling entirely: 4 threads per input row, each thread
// computes the (cheap) Rodrigues terms redundantly and writes exactly ONE
// float4 at its own lane-consecutive global index. Perfectly coalesced
// stores with no LDS and no barriers; waves stream independently.
// The 4x-duplicated 24B row reads hit the same cache lines (L1 absorbs).

__global__ void __launch_bounds__(256)
so3_to_mat_kernel(const float* __restrict__ x, float* __restrict__ out, int n4) {
    const int stride = gridDim.x * blockDim.x;
    float4* __restrict__ o4 = reinterpret_cast<float4*>(out);

    for (int g = blockIdx.x * blockDim.x + threadIdx.x; g < n4; g += stride) {
        const int row = g >> 2;   // input row
        const int k   = g & 3;    // which output row of the 4x4

        const float2* xr = reinterpret_cast<const float2*>(x) + 3 * (size_t)row;
        const float2 p0 = xr[0];
        const float2 p1 = xr[1];
        const float2 p2 = xr[2];
        const float wx = p0.x, wy = p0.y, wz = p1.x;
        const float tx = p1.y, ty = p2.x, tz = p2.y;

        const float t2 = wx * wx + wy * wy + wz * wz;
        const bool small = t2 < 1e-8f;

        const float th = sqrtf(small ? 1.0f : t2);
        float s, c;
        sincosf(th, &s, &c);
        const float A  = small ? (1.0f - t2 * (1.0f / 6.0f))  : (s / th);
        const float Bc = small ? (0.5f - t2 * (1.0f / 24.0f)) : ((1.0f - c) / t2);

        const float xx = wx * wx, yy = wy * wy, zz = wz * wz;
        const float xy = wx * wy, xz = wx * wz, yz = wy * wz;

        const float4 r0 = make_float4(1.0f - Bc * (yy + zz),
                                      -A * wz + Bc * xy,
                                       A * wy + Bc * xz,
                                      tx);
        const float4 r1 = make_float4( A * wz + Bc * xy,
                                      1.0f - Bc * (xx + zz),
                                      -A * wx + Bc * yz,
                                      ty);
        const float4 r2 = make_float4(-A * wy + Bc * xz,
                                       A * wx + Bc * yz,
                                      1.0f - Bc * (xx + yy),
                                      tz);
        const float4 r3 = make_float4(0.0f, 0.0f, 0.0f, 1.0f);

        // Branchless select of this lane's output row (k is lane-varying).
        float4 o = (k == 0) ? r0 : (k == 1) ? r1 : (k == 2) ? r2 : r3;
        o4[g] = o;
    }
}

extern "C" void kernel_launch(void* const* d_in, const int* in_sizes, int n_in,
                              void* d_out, int out_size, void* d_ws, size_t ws_size,
                              hipStream_t stream) {
    const float* x = (const float*)d_in[0];
    float* out = (float*)d_out;
    const int n = in_sizes[0] / 6;   // 4,000,000 rows
    const int n4 = 4 * n;           // 16,000,000 output float4s

    const int block = 256;
    int grid = (n4 + block - 1) / block;
    if (grid > 2048) grid = 2048;   // 8 blocks/CU, grid-stride (~31 iters)

    so3_to_mat_kernel<<<grid, block, 0, stream>>>(x, out, n4);
}

// Round 5
// 69.126 us; speedup vs baseline: 1.0826x; 1.0826x over previous
//
#include <hip/hip_runtime.h>

// SO(3) exp map (Rodrigues) + translation -> 4x4 matrix.
// Input:  x[B][6] f32  (w = x[:,0:3], t = x[:,3:6])
// Output: out[B][4][4] f32 row-major.
//
// Structure = round-1 winner: LDS-staged, fully-coalesced float4 stores.
// Round-4 lesson: 4x-redundant compute regressed => transcendental/VALU
// latency is partially on the critical path. This round cuts per-row math:
//   sincosf  -> __sinf/__cosf (hardware v_sin_f32/v_cos_f32, ~1e-6 abs err;
//               test threshold is 1e-1)
//   s/th     -> s * v_rsq_f32(t2)
//   (1-c)/t2 -> (1-c) * v_rcp_f32(t2)
//   sqrtf    -> th = t2 * rsq(t2)

#define TPB 256
#define P4 258  // padded row length (float4) for the LDS transpose buffer

__global__ void __launch_bounds__(TPB)
so3_to_mat_kernel(const float* __restrict__ x, float* __restrict__ out, int n) {
    __shared__ float4 buf[4 * P4];  // buf[s*P4 + r] = float4 #s of tile-row r
    const int t = threadIdx.x;
    const int ntiles = (n + TPB - 1) / TPB;

    for (int tile = blockIdx.x; tile < ntiles; tile += gridDim.x) {
        const int base = tile * TPB;
        const int row = base + t;

        if (row < n) {
            // Row occupies 24 B at x + 6*row; 8-B aligned -> three float2 loads.
            const float2* xr = reinterpret_cast<const float2*>(x) + 3 * (size_t)row;
            const float2 p0 = xr[0];
            const float2 p1 = xr[1];
            const float2 p2 = xr[2];
            const float wx = p0.x, wy = p0.y, wz = p1.x;
            const float tx = p1.y, ty = p2.x, tz = p2.y;

            const float t2 = wx * wx + wy * wy + wz * wz;
            const bool small = t2 < 1e-8f;

            // Fast reciprocals / sqrt via transcendental pipe (1-ulp class).
            const float inv_th = __builtin_amdgcn_rsqf(small ? 1.0f : t2); // 1/theta
            const float inv_t2 = __builtin_amdgcn_rcpf(t2);                 // 1/theta^2
            const float th = (small ? 1.0f : t2) * inv_th;                  // theta

            const float s = __sinf(th);
            const float c = __cosf(th);

            const float A  = small ? (1.0f - t2 * (1.0f / 6.0f))  : (s * inv_th);
            const float Bc = small ? (0.5f - t2 * (1.0f / 24.0f)) : ((1.0f - c) * inv_t2);

            const float xx = wx * wx, yy = wy * wy, zz = wz * wz;
            const float xy = wx * wy, xz = wx * wz, yz = wy * wz;

            buf[0 * P4 + t] = make_float4(1.0f - Bc * (yy + zz),
                                          -A * wz + Bc * xy,
                                           A * wy + Bc * xz,
                                          tx);
            buf[1 * P4 + t] = make_float4( A * wz + Bc * xy,
                                          1.0f - Bc * (xx + zz),
                                          -A * wx + Bc * yz,
                                          ty);
            buf[2 * P4 + t] = make_float4(-A * wy + Bc * xz,
                                           A * wx + Bc * yz,
                                          1.0f - Bc * (xx + yy),
                                          tz);
            buf[3 * P4 + t] = make_float4(0.0f, 0.0f, 0.0f, 1.0f);
        }
        __syncthreads();

        // Coalesced write-out: 256 rows * 4 float4 = 1024 lane-consecutive float4.
        const int nrow = min(TPB, n - base);
        float4* ob = reinterpret_cast<float4*>(out) + 4 * (size_t)base;
        #pragma unroll
        for (int m = 0; m < 4; ++m) {
            const int g = t + TPB * m;
            if (g < 4 * nrow) {
                ob[g] = buf[(g & 3) * P4 + (g >> 2)];
            }
        }
        __syncthreads();  // protect LDS before next tile's writes
    }
}

extern "C" void kernel_launch(void* const* d_in, const int* in_sizes, int n_in,
                              void* d_out, int out_size, void* d_ws, size_t ws_size,
                              hipStream_t stream) {
    const float* x = (const float*)d_in[0];
    float* out = (float*)d_out;
    const int n = in_sizes[0] / 6;  // 4,000,000 rows

    const int ntiles = (n + TPB - 1) / TPB;
    int grid = ntiles < 2048 ? ntiles : 2048;  // 8 blocks/CU

    so3_to_mat_kernel<<<grid, TPB, 0, stream>>>(x, out, n);
}

// Round 7
// 56.233 us; speedup vs baseline: 1.3308x; 1.2293x over previous
//
#include <hip/hip_runtime.h>

// SO(3) exp map (Rodrigues) + translation -> 4x4 matrix.
// Input:  x[B][6] f32  (w = x[:,0:3], t = x[:,3:6])
// Output: out[B][4][4] f32 row-major.
//
// Structure = round-1/5 winner: LDS-staged, fully-coalesced float4 stores,
// hw-transcendental math. This round: NON-TEMPORAL output stores (nt flag,
// no L2/L3 write-allocate) via a native ext_vector float4 — the HIP
// vector_type overload doesn't exist for __builtin_nontemporal_store.

#define TPB 256
#define P4 258  // padded row length (float4) for the LDS transpose buffer

typedef float vfloat4 __attribute__((ext_vector_type(4)));

__global__ void __launch_bounds__(TPB)
so3_to_mat_kernel(const float* __restrict__ x, float* __restrict__ out, int n) {
    __shared__ vfloat4 buf[4 * P4];  // buf[s*P4 + r] = float4 #s of tile-row r
    const int t = threadIdx.x;
    const int ntiles = (n + TPB - 1) / TPB;

    for (int tile = blockIdx.x; tile < ntiles; tile += gridDim.x) {
        const int base = tile * TPB;
        const int row = base + t;

        if (row < n) {
            // Row occupies 24 B at x + 6*row; 8-B aligned -> three float2 loads.
            const float2* xr = reinterpret_cast<const float2*>(x) + 3 * (size_t)row;
            const float2 p0 = xr[0];
            const float2 p1 = xr[1];
            const float2 p2 = xr[2];
            const float wx = p0.x, wy = p0.y, wz = p1.x;
            const float tx = p1.y, ty = p2.x, tz = p2.y;

            const float t2 = wx * wx + wy * wy + wz * wz;
            const bool small = t2 < 1e-8f;

            // Fast reciprocals / sqrt via transcendental pipe.
            const float inv_th = __builtin_amdgcn_rsqf(small ? 1.0f : t2); // 1/theta
            const float inv_t2 = __builtin_amdgcn_rcpf(t2);                 // 1/theta^2
            const float th = (small ? 1.0f : t2) * inv_th;                  // theta

            const float s = __sinf(th);
            const float c = __cosf(th);

            const float A  = small ? (1.0f - t2 * (1.0f / 6.0f))  : (s * inv_th);
            const float Bc = small ? (0.5f - t2 * (1.0f / 24.0f)) : ((1.0f - c) * inv_t2);

            const float xx = wx * wx, yy = wy * wy, zz = wz * wz;
            const float xy = wx * wy, xz = wx * wz, yz = wy * wz;

            {
                vfloat4 v;
                v.x = 1.0f - Bc * (yy + zz); v.y = -A * wz + Bc * xy;
                v.z =  A * wy + Bc * xz;     v.w = tx;
                buf[0 * P4 + t] = v;
            }
            {
                vfloat4 v;
                v.x =  A * wz + Bc * xy;     v.y = 1.0f - Bc * (xx + zz);
                v.z = -A * wx + Bc * yz;     v.w = ty;
                buf[1 * P4 + t] = v;
            }
            {
                vfloat4 v;
                v.x = -A * wy + Bc * xz;     v.y =  A * wx + Bc * yz;
                v.z = 1.0f - Bc * (xx + yy); v.w = tz;
                buf[2 * P4 + t] = v;
            }
            {
                vfloat4 v;
                v.x = 0.0f; v.y = 0.0f; v.z = 0.0f; v.w = 1.0f;
                buf[3 * P4 + t] = v;
            }
        }
        __syncthreads();

        // Coalesced write-out: 256 rows * 4 float4 = 1024 lane-consecutive
        // float4, streamed with non-temporal stores (no L2/L3 allocation).
        const int nrow = min(TPB, n - base);
        vfloat4* ob = reinterpret_cast<vfloat4*>(out) + 4 * (size_t)base;
        #pragma unroll
        for (int m = 0; m < 4; ++m) {
            const int g = t + TPB * m;
            if (g < 4 * nrow) {
                __builtin_nontemporal_store(buf[(g & 3) * P4 + (g >> 2)], &ob[g]);
            }
        }
        __syncthreads();  // protect LDS before next tile's writes
    }
}

extern "C" void kernel_launch(void* const* d_in, const int* in_sizes, int n_in,
                              void* d_out, int out_size, void* d_ws, size_t ws_size,
                              hipStream_t stream) {
    const float* x = (const float*)d_in[0];
    float* out = (float*)d_out;
    const int n = in_sizes[0] / 6;  // 4,000,000 rows

    const int ntiles = (n + TPB - 1) / TPB;
    int grid = ntiles < 2048 ? ntiles : 2048;  // 8 blocks/CU

    so3_to_mat_kernel<<<grid, TPB, 0, stream>>>(x, out, n);
}